// Round 3
// baseline (257.347 us; speedup 1.0000x reference)
//
#include <hip/hip_runtime.h>
#include <math.h>

#define LRELU_ALPHA 0.2f

constexpr int B_ = 8;
constexpr int N_ = 2048;
constexpr int M_ = B_ * N_;      // 16384 rows total
constexpr int SEG = 32;          // ranks per segment
constexpr int NSEG = N_ / SEG;   // 64 segments per batch

// ---------------------------------------------------------------------------
// K1: h = text @ W (fp32), fused epilogue: s1 = h·a1, s2 = h·a2,
//     eN0 = exp(0.2*s2), eP0 = exp(s2).
// ---------------------------------------------------------------------------
__global__ __launch_bounds__(512) void k_gemm(const float* __restrict__ text,
                                              const float* __restrict__ W,
                                              const float* __restrict__ a,
                                              float* __restrict__ h,
                                              float* __restrict__ s1,
                                              float* __restrict__ s2,
                                              float* __restrict__ eN0,
                                              float* __restrict__ eP0) {
    __shared__ float As[64 * 33];
    __shared__ float Ws[32 * 128];
    const int tid = threadIdx.x;
    const int r0  = blockIdx.x * 64;
    const int cx  = tid & 15;
    const int ry  = tid >> 4;
    const int c0  = cx * 8;
    const int rr0 = ry * 2;

    float acc[2][8];
#pragma unroll
    for (int i = 0; i < 2; ++i)
#pragma unroll
        for (int j = 0; j < 8; ++j) acc[i][j] = 0.f;

    for (int kk = 0; kk < 128; kk += 32) {
        for (int idx = tid; idx < 64 * 32; idx += 512) {
            int r = idx >> 5, c = idx & 31;
            As[r * 33 + c] = text[(r0 + r) * 128 + kk + c];
        }
        for (int idx = tid; idx < 32 * 128; idx += 512) {
            int k = idx >> 7, f = idx & 127;
            Ws[k * 128 + f] = W[(kk + k) * 128 + f];
        }
        __syncthreads();
#pragma unroll
        for (int k = 0; k < 32; ++k) {
            float4 w0 = *(const float4*)&Ws[k * 128 + c0];
            float4 w1 = *(const float4*)&Ws[k * 128 + c0 + 4];
#pragma unroll
            for (int i = 0; i < 2; ++i) {
                float av = As[(rr0 + i) * 33 + k];
                acc[i][0] += av * w0.x; acc[i][1] += av * w0.y;
                acc[i][2] += av * w0.z; acc[i][3] += av * w0.w;
                acc[i][4] += av * w1.x; acc[i][5] += av * w1.y;
                acc[i][6] += av * w1.z; acc[i][7] += av * w1.w;
            }
        }
        __syncthreads();
    }

    float4 a10 = *(const float4*)&a[c0];
    float4 a11 = *(const float4*)&a[c0 + 4];
    float4 a20 = *(const float4*)&a[128 + c0];
    float4 a21 = *(const float4*)&a[128 + c0 + 4];

#pragma unroll
    for (int i = 0; i < 2; ++i) {
        int row = r0 + rr0 + i;
        float4 o0 = {acc[i][0], acc[i][1], acc[i][2], acc[i][3]};
        float4 o1 = {acc[i][4], acc[i][5], acc[i][6], acc[i][7]};
        *(float4*)&h[row * 128 + c0]     = o0;
        *(float4*)&h[row * 128 + c0 + 4] = o1;

        float p1 = o0.x * a10.x + o0.y * a10.y + o0.z * a10.z + o0.w * a10.w
                 + o1.x * a11.x + o1.y * a11.y + o1.z * a11.z + o1.w * a11.w;
        float p2 = o0.x * a20.x + o0.y * a20.y + o0.z * a20.z + o0.w * a20.w
                 + o1.x * a21.x + o1.y * a21.y + o1.z * a21.z + o1.w * a21.w;
#pragma unroll
        for (int off = 8; off >= 1; off >>= 1) {
            p1 += __shfl_xor(p1, off);
            p2 += __shfl_xor(p2, off);
        }
        if (cx == 0) {
            s1[row] = p1;
            s2[row] = p2;
            eN0[row] = expf(LRELU_ALPHA * p2);
            eP0[row] = expf(p2);
        }
    }
}

// ---------------------------------------------------------------------------
// K2: counting-rank + threshold stats + query bucketing.
//   myrank -> scatter perm/eNs/ePs (sorted order arrays)
//   r_i = #{k : s2_k <= -s1_i};  ZN_i, ZP_i masked scalar sums
//   bucket query i into segment min(r_i/SEG, NSEG-1) via atomicAdd.
// ---------------------------------------------------------------------------
__global__ __launch_bounds__(512) void k_rank(const float* __restrict__ s2,
                                              const float* __restrict__ eN0,
                                              const float* __restrict__ eP0,
                                              const float* __restrict__ s1,
                                              int* __restrict__ perm,
                                              float* __restrict__ eNs,
                                              float* __restrict__ ePs,
                                              int* __restrict__ rank,
                                              float* __restrict__ ZN,
                                              float* __restrict__ ZP,
                                              int* __restrict__ qcnt,
                                              int* __restrict__ qlist) {
    __shared__ float ls2[2048], leN[2048], leP[2048];
    __shared__ int   redc[512], redm[512];
    __shared__ float redn[512], redp[512];

    const int b  = blockIdx.x >> 5;
    const int eb = blockIdx.x & 31;
    const int tid = threadIdx.x;
    const int e = tid & 63;
    const int c = tid >> 6;            // chunk 0..7

    {
        const float4* g2 = (const float4*)(s2  + b * 2048);
        const float4* gn = (const float4*)(eN0 + b * 2048);
        const float4* gp = (const float4*)(eP0 + b * 2048);
        ((float4*)ls2)[tid] = g2[tid];
        ((float4*)leN)[tid] = gn[tid];
        ((float4*)leP)[tid] = gp[tid];
    }
    __syncthreads();

    const int i  = eb * 64 + e;
    const int gi = b * 2048 + i;
    const float myS2 = ls2[i];
    const float thr  = -s1[gi];

    int cnt = 0, mr = 0;
    float sn = 0.f, sp = 0.f;
    const int j0 = c * 256;
#pragma unroll 4
    for (int j = j0; j < j0 + 256; j += 4) {
        float4 v  = *(const float4*)&ls2[j];
        float4 en = *(const float4*)&leN[j];
        float4 ep = *(const float4*)&leP[j];
#define PROC(vv, ee, pp, jj)                                             \
        { bool le = (vv) <= thr;                                         \
          cnt += le ? 1 : 0;                                             \
          sn  += le ? (ee) : 0.f;                                        \
          sp  += le ? 0.f : (pp);                                        \
          mr  += ((vv) < myS2 || ((vv) == myS2 && (jj) < i)) ? 1 : 0; }
        PROC(v.x, en.x, ep.x, j + 0)
        PROC(v.y, en.y, ep.y, j + 1)
        PROC(v.z, en.z, ep.z, j + 2)
        PROC(v.w, en.w, ep.w, j + 3)
#undef PROC
    }
    redc[tid] = cnt; redm[tid] = mr; redn[tid] = sn; redp[tid] = sp;
    __syncthreads();
    if (c == 0) {
        int tc = 0, tm = 0; float tn = 0.f, tp = 0.f;
#pragma unroll
        for (int cc = 0; cc < 8; ++cc) {
            tc += redc[cc * 64 + e];
            tm += redm[cc * 64 + e];
            tn += redn[cc * 64 + e];
            tp += redp[cc * 64 + e];
        }
        perm[b * 2048 + tm] = i;
        eNs [b * 2048 + tm] = leN[i];
        ePs [b * 2048 + tm] = leP[i];
        rank[gi] = tc;
        ZN[gi] = tn;
        ZP[gi] = tp;
        int sq = tc >> 5; if (sq > NSEG - 1) sq = NSEG - 1;  // rank==2048 -> bucket 63
        int slot = atomicAdd(&qcnt[b * NSEG + sq], 1);
        qlist[(b * NSEG + sq) * 2048 + slot] = i;
    }
}

// ---------------------------------------------------------------------------
// K3: per (batch, segment) sums of eNs*h[perm] and ePs*h[perm].
// ---------------------------------------------------------------------------
__global__ __launch_bounds__(128) void k_segsum(const float* __restrict__ h,
                                                const int* __restrict__ perm,
                                                const float* __restrict__ eNs,
                                                const float* __restrict__ ePs,
                                                float* __restrict__ segN,
                                                float* __restrict__ segP) {
    const int blk = blockIdx.x;
    const int b = blk >> 6, s = blk & 63;
    const int f = threadIdx.x;
    const int rbase = s * SEG;
    float an = 0.f, ap = 0.f;
#pragma unroll 4
    for (int r = 0; r < SEG; ++r) {
        int rr = b * 2048 + rbase + r;
        float hv = h[(b * 2048 + perm[rr]) * 128 + f];
        an += eNs[rr] * hv;
        ap += ePs[rr] * hv;
    }
    segN[blk * 128 + f] = an;
    segP[blk * 128 + f] = ap;
}

// ---------------------------------------------------------------------------
// K4: fused prefix + epilogue. Per (batch, segment):
//   cn = sum_{ss<s} segN[ss], cp = sum_{ss>s} segP[ss]
//   local exclusive Pre / inclusive Suf scans in LDS (index l in [0,32])
//   for each query q bucketed here (rank in [s*SEG, s*SEG+SEG], incl. 2048
//   at s=63 -> l=32):
//     h' = (E1*(cp+SufL[l]) + E2*(cn+PreL[l])) / Z;  out = elu(h' + 0.2 h)
// ---------------------------------------------------------------------------
__global__ __launch_bounds__(128) void k_fused(const float* __restrict__ h,
                                               const int* __restrict__ perm,
                                               const float* __restrict__ eNs,
                                               const float* __restrict__ ePs,
                                               const float* __restrict__ segN,
                                               const float* __restrict__ segP,
                                               const int* __restrict__ qcnt,
                                               const int* __restrict__ qlist,
                                               const int* __restrict__ rank,
                                               const float* __restrict__ s1,
                                               const float* __restrict__ ZN,
                                               const float* __restrict__ ZP,
                                               float* __restrict__ out) {
    __shared__ float PreL[33 * 128];
    __shared__ float SufL[33 * 128];
    const int blk = blockIdx.x;
    const int b = blk >> 6, s = blk & 63;
    const int f = threadIdx.x;

    // global segment offsets (coalesced L2 reads, pipelined)
    float cn = 0.f, cp = 0.f;
    for (int ss = 0; ss < s; ++ss)         cn += segN[(b * NSEG + ss) * 128 + f];
    for (int ss = s + 1; ss < NSEG; ++ss)  cp += segP[(b * NSEG + ss) * 128 + f];

    // segment-local scans; h rows read once into registers
    float hv[SEG];
    float an = 0.f;
#pragma unroll
    for (int l = 0; l < SEG; ++l) {
        int rr = b * 2048 + s * SEG + l;
        hv[l] = h[(b * 2048 + perm[rr]) * 128 + f];
        PreL[l * 128 + f] = an;
        an += eNs[rr] * hv[l];
    }
    float ap = 0.f;
#pragma unroll
    for (int l = SEG - 1; l >= 0; --l) {
        int rr = b * 2048 + s * SEG + l;
        ap += ePs[rr] * hv[l];
        SufL[l * 128 + f] = ap;
    }
    PreL[SEG * 128 + f] = an;   // l == 32: end-of-segment (rank boundary)
    SufL[SEG * 128 + f] = 0.f;
    __syncthreads();

    const int nq = qcnt[b * NSEG + s];
    const int qbase = (b * NSEG + s) * 2048;
    for (int k = 0; k < nq; ++k) {
        int q  = qlist[qbase + k];
        int gq = b * 2048 + q;
        float s1v = s1[gq];
        float E1 = expf(s1v), E2 = expf(LRELU_ALPHA * s1v);
        float Z = E1 * ZP[gq] + E2 * ZN[gq];
        int l = rank[gq] - s * SEG;        // 0..32
        float PreAt = cn + PreL[l * 128 + f];
        float SufAt = cp + SufL[l * 128 + f];
        float x = (E1 * SufAt + E2 * PreAt) / Z + LRELU_ALPHA * h[gq * 128 + f];
        out[gq * 128 + f] = (x > 0.f) ? x : expm1f(x);
    }
}

// ---------------------------------------------------------------------------
extern "C" void kernel_launch(void* const* d_in, const int* in_sizes, int n_in,
                              void* d_out, int out_size, void* d_ws, size_t ws_size,
                              hipStream_t stream) {
    const float* text = (const float*)d_in[0];
    // d_in[1] = adj : all-ones, unused by the reference math -> never read.
    const float* W = (const float*)d_in[2];
    const float* a = (const float*)d_in[3];
    float* out = (float*)d_out;

    float* p = (float*)d_ws;
    float* h    = p; p += (size_t)M_ * 128;
    float* s1   = p; p += M_;
    float* s2   = p; p += M_;
    float* eN0  = p; p += M_;
    float* eP0  = p; p += M_;
    int*   perm = (int*)p; p += M_;
    float* eNs  = p; p += M_;
    float* ePs  = p; p += M_;
    int*   rank = (int*)p; p += M_;
    float* ZN   = p; p += M_;
    float* ZP   = p; p += M_;
    float* segN = p; p += B_ * NSEG * 128;
    float* segP = p; p += B_ * NSEG * 128;
    int*   qcnt = (int*)p; p += B_ * NSEG;
    int*   qlist = (int*)p; p += (size_t)B_ * NSEG * 2048;

    hipMemsetAsync(qcnt, 0, B_ * NSEG * sizeof(int), stream);
    hipLaunchKernelGGL(k_gemm,   dim3(M_ / 64),   dim3(512), 0, stream,
                       text, W, a, h, s1, s2, eN0, eP0);
    hipLaunchKernelGGL(k_rank,   dim3(B_ * 32),   dim3(512), 0, stream,
                       s2, eN0, eP0, s1, perm, eNs, ePs, rank, ZN, ZP, qcnt, qlist);
    hipLaunchKernelGGL(k_segsum, dim3(B_ * NSEG), dim3(128), 0, stream,
                       h, perm, eNs, ePs, segN, segP);
    hipLaunchKernelGGL(k_fused,  dim3(B_ * NSEG), dim3(128), 0, stream,
                       h, perm, eNs, ePs, segN, segP, qcnt, qlist, rank, s1, ZN, ZP, out);
}

// Round 4
// 235.680 us; speedup vs baseline: 1.0919x; 1.0919x over previous
//
#include <hip/hip_runtime.h>
#include <hip/hip_bf16.h>
#include <math.h>

#define LRELU_ALPHA 0.2f

constexpr int B_ = 8;
constexpr int N_ = 2048;
constexpr int M_ = B_ * N_;      // 16384 rows total
constexpr int SEG = 32;          // ranks per segment for the vector scans
constexpr int NSEG = N_ / SEG;   // 64 segments per batch

// ---------------------------------------------------------------------------
// K1: h = text @ W (fp32), fused epilogue: s1 = h·a1, s2 = h·a2,
//     eN0 = exp(0.2*s2), eP0 = exp(s2).
// ---------------------------------------------------------------------------
__global__ __launch_bounds__(512) void k_gemm(const float* __restrict__ text,
                                              const float* __restrict__ W,
                                              const float* __restrict__ a,
                                              float* __restrict__ h,
                                              float* __restrict__ s1,
                                              float* __restrict__ s2,
                                              float* __restrict__ eN0,
                                              float* __restrict__ eP0) {
    __shared__ float As[64 * 33];
    __shared__ float Ws[32 * 128];
    const int tid = threadIdx.x;
    const int r0  = blockIdx.x * 64;
    const int cx  = tid & 15;
    const int ry  = tid >> 4;
    const int c0  = cx * 8;
    const int rr0 = ry * 2;

    float acc[2][8];
#pragma unroll
    for (int i = 0; i < 2; ++i)
#pragma unroll
        for (int j = 0; j < 8; ++j) acc[i][j] = 0.f;

    for (int kk = 0; kk < 128; kk += 32) {
        for (int idx = tid; idx < 64 * 32; idx += 512) {
            int r = idx >> 5, c = idx & 31;
            As[r * 33 + c] = text[(r0 + r) * 128 + kk + c];
        }
        for (int idx = tid; idx < 32 * 128; idx += 512) {
            int k = idx >> 7, f = idx & 127;
            Ws[k * 128 + f] = W[(kk + k) * 128 + f];
        }
        __syncthreads();
#pragma unroll
        for (int k = 0; k < 32; ++k) {
            float4 w0 = *(const float4*)&Ws[k * 128 + c0];
            float4 w1 = *(const float4*)&Ws[k * 128 + c0 + 4];
#pragma unroll
            for (int i = 0; i < 2; ++i) {
                float av = As[(rr0 + i) * 33 + k];
                acc[i][0] += av * w0.x; acc[i][1] += av * w0.y;
                acc[i][2] += av * w0.z; acc[i][3] += av * w0.w;
                acc[i][4] += av * w1.x; acc[i][5] += av * w1.y;
                acc[i][6] += av * w1.z; acc[i][7] += av * w1.w;
            }
        }
        __syncthreads();
    }

    float4 a10 = *(const float4*)&a[c0];
    float4 a11 = *(const float4*)&a[c0 + 4];
    float4 a20 = *(const float4*)&a[128 + c0];
    float4 a21 = *(const float4*)&a[128 + c0 + 4];

#pragma unroll
    for (int i = 0; i < 2; ++i) {
        int row = r0 + rr0 + i;
        float4 o0 = {acc[i][0], acc[i][1], acc[i][2], acc[i][3]};
        float4 o1 = {acc[i][4], acc[i][5], acc[i][6], acc[i][7]};
        *(float4*)&h[row * 128 + c0]     = o0;
        *(float4*)&h[row * 128 + c0 + 4] = o1;

        float p1 = o0.x * a10.x + o0.y * a10.y + o0.z * a10.z + o0.w * a10.w
                 + o1.x * a11.x + o1.y * a11.y + o1.z * a11.z + o1.w * a11.w;
        float p2 = o0.x * a20.x + o0.y * a20.y + o0.z * a20.z + o0.w * a20.w
                 + o1.x * a21.x + o1.y * a21.y + o1.z * a21.z + o1.w * a21.w;
#pragma unroll
        for (int off = 8; off >= 1; off >>= 1) {
            p1 += __shfl_xor(p1, off);
            p2 += __shfl_xor(p2, off);
        }
        if (cx == 0) {
            s1[row] = p1;
            s2[row] = p2;
            eN0[row] = expf(LRELU_ALPHA * p2);
            eP0[row] = expf(p2);
        }
    }
}

// ---------------------------------------------------------------------------
// K2: counting-rank kernel (unchanged from R2).
// ---------------------------------------------------------------------------
__global__ __launch_bounds__(512) void k_rank(const float* __restrict__ s2,
                                              const float* __restrict__ eN0,
                                              const float* __restrict__ eP0,
                                              const float* __restrict__ s1,
                                              int* __restrict__ perm,
                                              float* __restrict__ eNs,
                                              float* __restrict__ ePs,
                                              int* __restrict__ rank,
                                              float* __restrict__ ZN,
                                              float* __restrict__ ZP) {
    __shared__ float ls2[2048], leN[2048], leP[2048];
    __shared__ int   redc[512], redm[512];
    __shared__ float redn[512], redp[512];

    const int b  = blockIdx.x >> 5;
    const int eb = blockIdx.x & 31;
    const int tid = threadIdx.x;
    const int e = tid & 63;
    const int c = tid >> 6;            // chunk 0..7

    {
        const float4* g2 = (const float4*)(s2  + b * 2048);
        const float4* gn = (const float4*)(eN0 + b * 2048);
        const float4* gp = (const float4*)(eP0 + b * 2048);
        ((float4*)ls2)[tid] = g2[tid];
        ((float4*)leN)[tid] = gn[tid];
        ((float4*)leP)[tid] = gp[tid];
    }
    __syncthreads();

    const int i  = eb * 64 + e;
    const int gi = b * 2048 + i;
    const float myS2 = ls2[i];
    const float thr  = -s1[gi];

    int cnt = 0, mr = 0;
    float sn = 0.f, sp = 0.f;
    const int j0 = c * 256;
#pragma unroll 4
    for (int j = j0; j < j0 + 256; j += 4) {
        float4 v  = *(const float4*)&ls2[j];
        float4 en = *(const float4*)&leN[j];
        float4 ep = *(const float4*)&leP[j];
#define PROC(vv, ee, pp, jj)                                             \
        { bool le = (vv) <= thr;                                         \
          cnt += le ? 1 : 0;                                             \
          sn  += le ? (ee) : 0.f;                                        \
          sp  += le ? 0.f : (pp);                                        \
          mr  += ((vv) < myS2 || ((vv) == myS2 && (jj) < i)) ? 1 : 0; }
        PROC(v.x, en.x, ep.x, j + 0)
        PROC(v.y, en.y, ep.y, j + 1)
        PROC(v.z, en.z, ep.z, j + 2)
        PROC(v.w, en.w, ep.w, j + 3)
#undef PROC
    }
    redc[tid] = cnt; redm[tid] = mr; redn[tid] = sn; redp[tid] = sp;
    __syncthreads();
    if (c == 0) {
        int tc = 0, tm = 0; float tn = 0.f, tp = 0.f;
#pragma unroll
        for (int cc = 0; cc < 8; ++cc) {
            tc += redc[cc * 64 + e];
            tm += redm[cc * 64 + e];
            tn += redn[cc * 64 + e];
            tp += redp[cc * 64 + e];
        }
        perm[b * 2048 + tm] = i;
        eNs [b * 2048 + tm] = leN[i];
        ePs [b * 2048 + tm] = leP[i];
        rank[gi] = tc;
        ZN[gi] = tn;
        ZP[gi] = tp;
    }
}

// ---------------------------------------------------------------------------
// K3: per (batch, segment) sums of eNs*h[perm] and ePs*h[perm].
// ---------------------------------------------------------------------------
__global__ __launch_bounds__(128) void k_segsum(const float* __restrict__ h,
                                                const int* __restrict__ perm,
                                                const float* __restrict__ eNs,
                                                const float* __restrict__ ePs,
                                                float* __restrict__ segN,
                                                float* __restrict__ segP) {
    const int blk = blockIdx.x;
    const int b = blk >> 6, s = blk & 63;
    const int f = threadIdx.x;
    const int rbase = s * SEG;
    float an = 0.f, ap = 0.f;
#pragma unroll 4
    for (int r = 0; r < SEG; ++r) {
        int rr = b * 2048 + rbase + r;
        float hv = h[(b * 2048 + perm[rr]) * 128 + f];
        an += eNs[rr] * hv;
        ap += ePs[rr] * hv;
    }
    segN[blk * 128 + f] = an;
    segP[blk * 128 + f] = ap;
}

// ---------------------------------------------------------------------------
// K4: full vector prefix/suffix arrays, stored BF16 (accumulated fp32).
//   Pre[b][r][f] = sum_{k<r}  eNs[k]*h[perm[k]][f]   (r in [0,2048])
//   Suf[b][r][f] = sum_{k>=r} ePs[k]*h[perm[k]][f]
// ---------------------------------------------------------------------------
__global__ __launch_bounds__(128) void k_prefix(const float* __restrict__ h,
                                                const int* __restrict__ perm,
                                                const float* __restrict__ eNs,
                                                const float* __restrict__ ePs,
                                                const float* __restrict__ segN,
                                                const float* __restrict__ segP,
                                                __hip_bfloat16* __restrict__ Pre,
                                                __hip_bfloat16* __restrict__ Suf) {
    const int blk = blockIdx.x;
    const int b = blk >> 6, s = blk & 63;
    const int f = threadIdx.x;
    const int rbase = s * SEG;

    float an = 0.f, ap = 0.f;
    for (int ss = 0; ss < s; ++ss)        an += segN[(b * NSEG + ss) * 128 + f];
    for (int ss = s + 1; ss < NSEG; ++ss) ap += segP[(b * NSEG + ss) * 128 + f];

    float hv[SEG];
#pragma unroll
    for (int r = 0; r < SEG; ++r) {
        int rr = b * 2048 + rbase + r;
        hv[r] = h[(b * 2048 + perm[rr]) * 128 + f];
        Pre[(size_t)(b * 2049 + rbase + r) * 128 + f] = __float2bfloat16(an);
        an += eNs[rr] * hv[r];
    }
#pragma unroll
    for (int r = SEG - 1; r >= 0; --r) {
        int rr = b * 2048 + rbase + r;
        ap += ePs[rr] * hv[r];
        Suf[(size_t)(b * 2049 + rbase + r) * 128 + f] = __float2bfloat16(ap);
    }
    if (s == NSEG - 1) {
        Pre[(size_t)(b * 2049 + 2048) * 128 + f] = __float2bfloat16(an);
        Suf[(size_t)(b * 2049 + 2048) * 128 + f] = __float2bfloat16(0.f);
    }
}

// ---------------------------------------------------------------------------
// K5: out = elu(h' + 0.2 h),  h' = (E1*Suf[r] + E2*Pre[r]) / (E1*ZP + E2*ZN)
// ---------------------------------------------------------------------------
__global__ __launch_bounds__(256) void k_out(const float* __restrict__ h,
                                             const float* __restrict__ s1,
                                             const int* __restrict__ rank,
                                             const float* __restrict__ ZN,
                                             const float* __restrict__ ZP,
                                             const __hip_bfloat16* __restrict__ Pre,
                                             const __hip_bfloat16* __restrict__ Suf,
                                             float* __restrict__ out) {
    const int tid = threadIdx.x;
    const int lr = tid >> 7, f = tid & 127;
    const int i = blockIdx.x * 2 + lr;
    const int b = i >> 11;

    const float s1v = s1[i];
    const float E1 = expf(s1v);
    const float E2 = expf(LRELU_ALPHA * s1v);
    const int   r  = rank[i];
    const float Z  = E1 * ZP[i] + E2 * ZN[i];
    const size_t o = (size_t)(b * 2049 + r) * 128 + f;
    const float hp = (E1 * __bfloat162float(Suf[o]) + E2 * __bfloat162float(Pre[o])) / Z;
    const float x = hp + LRELU_ALPHA * h[i * 128 + f];
    out[i * 128 + f] = (x > 0.f) ? x : expm1f(x);
}

// ---------------------------------------------------------------------------
extern "C" void kernel_launch(void* const* d_in, const int* in_sizes, int n_in,
                              void* d_out, int out_size, void* d_ws, size_t ws_size,
                              hipStream_t stream) {
    const float* text = (const float*)d_in[0];
    // d_in[1] = adj : all-ones, unused by the reference math -> never read.
    const float* W = (const float*)d_in[2];
    const float* a = (const float*)d_in[3];
    float* out = (float*)d_out;

    float* p = (float*)d_ws;
    float* h    = p; p += (size_t)M_ * 128;
    float* s1   = p; p += M_;
    float* s2   = p; p += M_;
    float* eN0  = p; p += M_;
    float* eP0  = p; p += M_;
    int*   perm = (int*)p; p += M_;
    float* eNs  = p; p += M_;
    float* ePs  = p; p += M_;
    int*   rank = (int*)p; p += M_;
    float* ZN   = p; p += M_;
    float* ZP   = p; p += M_;
    float* segN = p; p += B_ * NSEG * 128;
    float* segP = p; p += B_ * NSEG * 128;
    __hip_bfloat16* Pre = (__hip_bfloat16*)p; p += (size_t)B_ * 2049 * 128 / 2;
    __hip_bfloat16* Suf = (__hip_bfloat16*)p; p += (size_t)B_ * 2049 * 128 / 2;

    hipLaunchKernelGGL(k_gemm,   dim3(M_ / 64),   dim3(512), 0, stream,
                       text, W, a, h, s1, s2, eN0, eP0);
    hipLaunchKernelGGL(k_rank,   dim3(B_ * 32),   dim3(512), 0, stream,
                       s2, eN0, eP0, s1, perm, eNs, ePs, rank, ZN, ZP);
    hipLaunchKernelGGL(k_segsum, dim3(B_ * NSEG), dim3(128), 0, stream,
                       h, perm, eNs, ePs, segN, segP);
    hipLaunchKernelGGL(k_prefix, dim3(B_ * NSEG), dim3(128), 0, stream,
                       h, perm, eNs, ePs, segN, segP, Pre, Suf);
    hipLaunchKernelGGL(k_out,    dim3(M_ / 2),    dim3(256), 0, stream,
                       h, s1, rank, ZN, ZP, Pre, Suf, out);
}